// Round 4
// baseline (713.726 us; speedup 1.0000x reference)
//
#include <hip/hip_runtime.h>

#define NNODES 65536
#define INC    512
#define NH     4
#define HD     256
#define HDTOT  1024

typedef __bf16 bf16_t;
typedef __bf16 bf16x4_t __attribute__((ext_vector_type(4)));
typedef __bf16 bf16x8_t __attribute__((ext_vector_type(8)));
typedef float  f32x4_t  __attribute__((ext_vector_type(4)));

__device__ __forceinline__ bf16_t f2bf(float f) { return (bf16_t)f; }

__device__ __forceinline__ void gl_lds16(const void* g, void* l) {
  __builtin_amdgcn_global_load_lds(
      (const __attribute__((address_space(1))) void*)g,
      (__attribute__((address_space(3))) void*)l, 16, 0, 0);
}

// ---------------- K0a: W [512][1024] f32 -> Wt [mat][1024][512] bf16 (transposed) ----
__global__ void k0_wt(const float* __restrict__ Wq, const float* __restrict__ Wk,
                      const float* __restrict__ Wv, bf16_t* __restrict__ Wt) {
  __shared__ float tile[32][33];
  int mat = blockIdx.z;
  const float* W = (mat == 0) ? Wq : (mat == 1) ? Wk : Wv;
  int n0 = blockIdx.x * 32, k0 = blockIdx.y * 32;
  int t = threadIdx.x, tc = t & 31, tr = t >> 5;
#pragma unroll
  for (int i = 0; i < 4; ++i)
    tile[tr + i * 8][tc] = W[(size_t)(k0 + tr + i * 8) * HDTOT + n0 + tc];
  __syncthreads();
#pragma unroll
  for (int i = 0; i < 4; ++i)
    Wt[((size_t)mat * HDTOT + n0 + tr + i * 8) * INC + k0 + tc] =
        f2bf(tile[tc][tr + i * 8]);
}

// ---------------- K0b: x f32 -> xb bf16 ----------------------------------------------
__global__ void k0b_xb(const float* __restrict__ x, bf16_t* __restrict__ xb) {
  size_t i = ((size_t)blockIdx.x * 256 + threadIdx.x) * 8;
  float4 a = *(const float4*)(x + i);
  float4 b = *(const float4*)(x + i + 4);
  bf16x8_t o;
  o[0] = f2bf(a.x); o[1] = f2bf(a.y); o[2] = f2bf(a.z); o[3] = f2bf(a.w);
  o[4] = f2bf(b.x); o[5] = f2bf(b.y); o[6] = f2bf(b.z); o[7] = f2bf(b.w);
  *(bf16x8_t*)(xb + i) = o;
}

// ---------------- K1: QKV projection + bias + q/k row-L2-normalize ------------------
// grid 6144 1-D, XCD-swizzled: xcd = bid&7 owns 64 slabs walked slab-major so the
// xb slab (128KB) + Wt (3MB) stay L2-resident per XCD. 8 waves, wave tile 64x64,
// BK=32 dbuf, counted-vmcnt prefetch (2-deep, vmcnt(3)).
__global__ __launch_bounds__(512, 4) void k1_qkv(
    const bf16_t* __restrict__ xb, const bf16_t* __restrict__ Wt,
    const float* __restrict__ bq, const float* __restrict__ bk,
    const float* __restrict__ bv,
    bf16_t* __restrict__ qn, bf16_t* __restrict__ knT2, bf16_t* __restrict__ vT2,
    float* __restrict__ ksum, float* __restrict__ vsum) {
  __shared__ __align__(16) char smem[52224];
  // bufA[2]: [128][64B] @ 0, 8192 ; bufB[2]: [256][64B] @ 16384, 32768
  bf16_t* ept  = (bf16_t*)smem;            // epilogue tile [64][264|258]
  float* sred  = (float*)(smem + 49152);   // [128][4]
  float* sredc = (float*)(smem + 51200);   // [256]

  const int bid = blockIdx.x;
  const int xcd = bid & 7, pos = bid >> 3;
  const int gxy = pos % 12;                // mat*4+head (fast: L2 reuse of xb slab)
  const int mat = gxy >> 2, head = gxy & 3;
  const int n0 = (xcd * 64 + pos / 12) * 128;
  const int t = threadIdx.x;
  const int wid = t >> 6, lane = t & 63;
  const int l15 = lane & 15, l4 = lane >> 4;
  const int wr = wid >> 2, wc = wid & 3;

  const f32x4_t zero4 = {0.f, 0.f, 0.f, 0.f};
  f32x4_t acc[4][4];
#pragma unroll
  for (int i = 0; i < 4; ++i)
#pragma unroll
    for (int j = 0; j < 4; ++j) acc[i][j] = zero4;

  const char* Ab = (const char*)(xb + (size_t)n0 * INC);
  const char* Bb = (const char*)(Wt + ((size_t)mat * HDTOT + head * HD) * INC);

  auto stage = [&](int kt, int c) {
    const int kb = kt * 64;
    {
      int o = t * 16, r = o >> 6, cb = o & 63;
      gl_lds16(Ab + (size_t)r * 1024 + kb + (cb ^ ((r & 3) << 4)), smem + c * 8192 + o);
    }
#pragma unroll
    for (int i = 0; i < 2; ++i) {
      int o = i * 8192 + t * 16, r = o >> 6, cb = o & 63;
      gl_lds16(Bb + (size_t)r * 1024 + kb + (cb ^ ((r & 3) << 4)),
               smem + 16384 + c * 16384 + o);
    }
  };

  stage(0, 0);
  stage(1, 1);
  for (int kt = 0; kt < 16; ++kt) {
    const int cur = kt & 1;
    if (kt == 15) asm volatile("s_waitcnt vmcnt(0)" ::: "memory");
    else          asm volatile("s_waitcnt vmcnt(3)" ::: "memory");
    __builtin_amdgcn_s_barrier();
    __builtin_amdgcn_sched_barrier(0);
    const char* lA = smem + cur * 8192;
    const char* lB = smem + 16384 + cur * 16384;
    bf16x8_t af[4], bfr[4];
#pragma unroll
    for (int i = 0; i < 4; ++i) {
      int r = wr * 64 + i * 16 + l15;
      af[i] = *(const bf16x8_t*)(lA + r * 64 + ((l4 * 16) ^ ((r & 3) << 4)));
    }
#pragma unroll
    for (int j = 0; j < 4; ++j) {
      int r = wc * 64 + j * 16 + l15;
      bfr[j] = *(const bf16x8_t*)(lB + r * 64 + ((l4 * 16) ^ ((r & 3) << 4)));
    }
    __builtin_amdgcn_s_setprio(1);
#pragma unroll
    for (int i = 0; i < 4; ++i)
#pragma unroll
      for (int j = 0; j < 4; ++j)
        acc[i][j] = __builtin_amdgcn_mfma_f32_16x16x32_bf16(af[i], bfr[j], acc[i][j], 0, 0, 0);
    __builtin_amdgcn_s_setprio(0);
    __builtin_amdgcn_s_barrier();
    __builtin_amdgcn_sched_barrier(0);
    if (kt < 14) stage(kt + 2, cur);
  }

  // bias: col = wc*64 + jf*16 + l15
  const float* bias = (mat == 0) ? bq : (mat == 1) ? bk : bv;
#pragma unroll
  for (int jf = 0; jf < 4; ++jf) {
    float bb = bias[head * HD + wc * 64 + jf * 16 + l15];
#pragma unroll
    for (int i = 0; i < 4; ++i)
#pragma unroll
      for (int jj = 0; jj < 4; ++jj) acc[i][jf][jj] += bb;
  }

  // L2 row-normalize (q, k). Rows span 4 waves (wc) -> LDS reduce.
  if (mat <= 1) {
    float ss[4][4];
#pragma unroll
    for (int i = 0; i < 4; ++i)
#pragma unroll
      for (int jj = 0; jj < 4; ++jj) {
        float s = 0.f;
#pragma unroll
        for (int jf = 0; jf < 4; ++jf) s += acc[i][jf][jj] * acc[i][jf][jj];
        ss[i][jj] = s;
      }
#pragma unroll
    for (int off = 1; off < 16; off <<= 1)
#pragma unroll
      for (int i = 0; i < 4; ++i)
#pragma unroll
        for (int jj = 0; jj < 4; ++jj) ss[i][jj] += __shfl_xor(ss[i][jj], off, 64);
    if (l15 == 0) {
#pragma unroll
      for (int i = 0; i < 4; ++i)
#pragma unroll
        for (int jj = 0; jj < 4; ++jj)
          sred[(wr * 64 + i * 16 + l4 * 4 + jj) * 4 + wc] = ss[i][jj];
    }
    __syncthreads();
#pragma unroll
    for (int i = 0; i < 4; ++i)
#pragma unroll
      for (int jj = 0; jj < 4; ++jj) {
        int row = wr * 64 + i * 16 + l4 * 4 + jj;
        float s = sred[row * 4] + sred[row * 4 + 1] + sred[row * 4 + 2] + sred[row * 4 + 3];
        float rn = rsqrtf(s);
#pragma unroll
        for (int jf = 0; jf < 4; ++jf) acc[i][jf][jj] *= rn;
      }
  }

  // column sums (ksum from normalized k, vsum from v)
  if (mat >= 1) {
    float cs[4];
#pragma unroll
    for (int jf = 0; jf < 4; ++jf) {
      float s = 0.f;
#pragma unroll
      for (int i = 0; i < 4; ++i)
#pragma unroll
        for (int jj = 0; jj < 4; ++jj) s += acc[i][jf][jj];
      s += __shfl_xor(s, 16, 64);
      s += __shfl_xor(s, 32, 64);
      cs[jf] = s;
    }
    if (t < 256) sredc[t] = 0.f;
    __syncthreads();
    if (l4 == 0) {
#pragma unroll
      for (int jf = 0; jf < 4; ++jf)
        atomicAdd(&sredc[wc * 64 + jf * 16 + l15], cs[jf]);
    }
    __syncthreads();
    float* dstSum = (mat == 1) ? ksum : vsum;
    if (t < 256) atomicAdd(dstSum + head * HD + t, sredc[t]);
  }

  // write-out in two 64-row halves via LDS (coalesced; kn/v tile-chunked transposed)
  const int ldp = (mat == 0) ? 264 : 258;
  for (int ph = 0; ph < 2; ++ph) {
    __syncthreads();
    if (wr == ph) {
#pragma unroll
      for (int i = 0; i < 4; ++i)
#pragma unroll
        for (int jf = 0; jf < 4; ++jf)
#pragma unroll
          for (int jj = 0; jj < 4; ++jj)
            ept[(i * 16 + l4 * 4 + jj) * ldp + wc * 64 + jf * 16 + l15] =
                f2bf(acc[i][jf][jj]);
    }
    __syncthreads();
    const int hn0 = n0 + ph * 64;
    if (mat == 0) {
#pragma unroll
      for (int i = 0; i < 4; ++i) {
        int idx = t + i * 512;
        int r = idx >> 5, c8 = (idx & 31) * 8;
        *(bf16x8_t*)(qn + (size_t)(hn0 + r) * HDTOT + head * HD + c8) =
            *(const bf16x8_t*)(ept + r * 264 + c8);
      }
    } else {
      int m = t & 255, seg = t >> 8;
      bf16_t* dst = (mat == 1) ? knT2 : vT2;
      unsigned int pack[16];
#pragma unroll
      for (int rr = 0; rr < 32; rr += 2) {
        int r = seg * 32 + rr;
        unsigned int a = *(const unsigned short*)(ept + r * 258 + m);
        unsigned int b = *(const unsigned short*)(ept + (r + 1) * 258 + m);
        pack[rr >> 1] = a | (b << 16);
      }
      size_t base = ((((size_t)(head * 2 + (m >> 7)) * 1024 + (hn0 >> 6)) * 128 +
                      (m & 127)) * 64) + seg * 32;
      uint4* dp = (uint4*)(dst + base);
#pragma unroll
      for (int i = 0; i < 4; ++i)
        dp[i] = make_uint4(pack[i * 4], pack[i * 4 + 1], pack[i * 4 + 2], pack[i * 4 + 3]);
    }
  }
}

// ---------------- K2: kv partials = v^T kn over node chunks (contiguous tiles) ------
// grid (4, 4 heads, 32 chunks), 4 waves (2x2), tile 128x128, BK=64.
// Counted-vmcnt 2-deep prefetch (8 loads/stage -> vmcnt(8)).
__global__ __launch_bounds__(256, 4) void k2_kv(
    const bf16_t* __restrict__ knT2, const bf16_t* __restrict__ vT2,
    float* __restrict__ kvP) {
  __shared__ __align__(16) char smem[65536];  // bufA[2]@0,16384 ; bufB[2]@32768,49152

  const int gx = blockIdx.x;
  const int head = blockIdx.y, ch = blockIdx.z;
  const int td = gx >> 1, tm = gx & 1;

  const int t = threadIdx.x, wid = t >> 6, lane = t & 63;
  const int l15 = lane & 15, l4 = lane >> 4;
  const int wr = wid >> 1, wc = wid & 1;

  const f32x4_t zero4 = {0.f, 0.f, 0.f, 0.f};
  f32x4_t acc[4][4];
#pragma unroll
  for (int i = 0; i < 4; ++i)
#pragma unroll
    for (int j = 0; j < 4; ++j) acc[i][j] = zero4;

  const char* Abase = (const char*)vT2  + ((size_t)(head * 2 + td) * 1024 + ch * 32) * 16384;
  const char* Bbase = (const char*)knT2 + ((size_t)(head * 2 + tm) * 1024 + ch * 32) * 16384;

  auto stage = [&](int it, int c) {
#pragma unroll
    for (int i = 0; i < 4; ++i) {
      int o = i * 4096 + t * 16, r = o >> 7, cb = o & 127;
      int so = r * 128 + (cb ^ ((r & 7) << 4));
      gl_lds16(Abase + (size_t)it * 16384 + so, smem + c * 16384 + o);
      gl_lds16(Bbase + (size_t)it * 16384 + so, smem + 32768 + c * 16384 + o);
    }
  };

  stage(0, 0);
  stage(1, 1);
  for (int it = 0; it < 32; ++it) {
    const int cur = it & 1;
    if (it == 31) asm volatile("s_waitcnt vmcnt(0)" ::: "memory");
    else          asm volatile("s_waitcnt vmcnt(8)" ::: "memory");
    __builtin_amdgcn_s_barrier();
    __builtin_amdgcn_sched_barrier(0);
    const char* lA = smem + cur * 16384;
    const char* lB = smem + 32768 + cur * 16384;
#pragma unroll
    for (int ks = 0; ks < 2; ++ks) {
      bf16x8_t af[4], bfr[4];
#pragma unroll
      for (int i = 0; i < 4; ++i) {
        int r = wr * 64 + i * 16 + l15;
        af[i] = *(const bf16x8_t*)(lA + r * 128 + ((ks * 64 + l4 * 16) ^ ((r & 7) << 4)));
      }
#pragma unroll
      for (int j = 0; j < 4; ++j) {
        int r = wc * 64 + j * 16 + l15;
        bfr[j] = *(const bf16x8_t*)(lB + r * 128 + ((ks * 64 + l4 * 16) ^ ((r & 7) << 4)));
      }
      __builtin_amdgcn_s_setprio(1);
#pragma unroll
      for (int i = 0; i < 4; ++i)
#pragma unroll
        for (int j = 0; j < 4; ++j)
          acc[i][j] = __builtin_amdgcn_mfma_f32_16x16x32_bf16(af[i], bfr[j], acc[i][j], 0, 0, 0);
      __builtin_amdgcn_s_setprio(0);
    }
    __builtin_amdgcn_s_barrier();
    __builtin_amdgcn_sched_barrier(0);
    if (it < 30) stage(it + 2, cur);
  }

  float* dst = kvP + ((size_t)(ch * 16 + head * 4 + gx)) * 16384;
#pragma unroll
  for (int i = 0; i < 4; ++i)
#pragma unroll
    for (int jj = 0; jj < 4; ++jj)
#pragma unroll
      for (int j = 0; j < 4; ++j)
        dst[(wr * 64 + i * 16 + l4 * 4 + j) * 128 + wc * 64 + jj * 16 + l15] =
            acc[i][jj][j];
}

// ---------------- K3: reduce 32 kv partials + convert to bf16 ------------------------
__global__ void k3_red(const float* __restrict__ kvP, bf16_t* __restrict__ kvTb) {
  int tid = blockIdx.x * 256 + threadIdx.x;  // 65536 threads, 4 outputs each
  int base = tid * 4;
  int m = base & 255, d = (base >> 8) & 255, h = base >> 16;
  int gx = ((d >> 7) << 1) | (m >> 7);
  int off = (d & 127) * 128 + (m & 127);
  f32x4_t s = {0.f, 0.f, 0.f, 0.f};
#pragma unroll
  for (int ch = 0; ch < 32; ++ch)
    s += *(const f32x4_t*)(kvP + (((size_t)(ch * 16 + h * 4 + gx)) << 14) + off);
  bf16x4_t b;
  b[0] = f2bf(s[0]); b[1] = f2bf(s[1]); b[2] = f2bf(s[2]); b[3] = f2bf(s[3]);
  *(bf16x4_t*)(kvTb + (size_t)base) = b;
}

// ---------------- K4: out = mean_h (qn@kv + vsum) / (qn.ksum + N) ---------------------
// grid (1024), 4 waves, block tile 64 rows x 256 d, wave tile 16x256.
// Early-issue (T14) pipeline: lb double-buffered, raw barriers, no mid-loop drains
// of in-flight prefetch except the required vmcnt(0) (prefetch issued a full phase early).
__global__ __launch_bounds__(256, 1) void k4_out(
    const bf16_t* __restrict__ qn, const bf16_t* __restrict__ kvTb,
    const float* __restrict__ ksum, const float* __restrict__ vsum,
    float* __restrict__ out) {
  __shared__ __align__(16) char smem[99584];
  // la [64][512B] @0 ; lb0 @32768 ; lb1 @65536 ; sdn @98304
  float* sdn = (float*)(smem + 98304);

  const int n0 = blockIdx.x * 64;
  const int t = threadIdx.x, wid = t >> 6, lane = t & 63;
  const int l15 = lane & 15, l4 = lane >> 4;

  const f32x4_t zero4 = {0.f, 0.f, 0.f, 0.f};
  f32x4_t oacc[16];
#pragma unroll
  for (int f = 0; f < 16; ++f) oacc[f] = zero4;

  const char* qb  = (const char*)qn + (size_t)n0 * 2048;
  const char* kvb = (const char*)kvTb;

  auto stage_la = [&](int h) {
#pragma unroll
    for (int i = 0; i < 8; ++i) {
      int o = i * 4096 + t * 16, r = o >> 9, cb = o & 511;
      int scb = (cb & 0x180) | ((cb & 0x7F) ^ ((r & 7) << 4));
      gl_lds16(qb + (size_t)r * 2048 + h * 512 + scb, smem + o);
    }
  };
  auto stage_lb = [&](int h, int mc, int buf) {
#pragma unroll
    for (int i = 0; i < 8; ++i) {
      int o = i * 4096 + t * 16, r = o >> 7, cb = o & 127;
      gl_lds16(kvb + (size_t)h * 131072 + (size_t)r * 512 + mc * 128 +
                   (cb ^ ((r & 7) << 4)),
               smem + 32768 + buf * 32768 + o);
    }
  };

  stage_la(0);
  stage_lb(0, 0, 0);
  for (int h = 0; h < NH; ++h) {
    f32x4_t hacc[16];
#pragma unroll
    for (int f = 0; f < 16; ++f) hacc[f] = zero4;
    float dnp = 0.f;

    for (int mc = 0; mc < 4; ++mc) {
      const int cur = mc & 1;
      asm volatile("s_waitcnt vmcnt(0)" ::: "memory");
      __builtin_amdgcn_s_barrier();
      __builtin_amdgcn_sched_barrier(0);
      if (mc < 3) stage_lb(h, mc + 1, cur ^ 1);  // early issue, lands during compute
      if (mc == 0) {  // denom partial from la (row r, m-range qd*64..+64)
        int r = t & 63, qd = t >> 6;
        float s = 0.f;
#pragma unroll
        for (int j = 0; j < 64; ++j) {
          int cb2 = (qd * 64 + j) * 2;
          int a = r * 512 + ((cb2 & 0x180) | ((cb2 & 0x7F) ^ ((r & 7) << 4)));
          s += (float)(*(const bf16_t*)(smem + a)) * ksum[h * HD + qd * 64 + j];
        }
        dnp = s;
      }
      const char* lb = smem + 32768 + cur * 32768;
#pragma unroll
      for (int ks = 0; ks < 2; ++ks) {
        int ra = wid * 16 + l15;
        bf16x8_t af = *(const bf16x8_t*)(
            smem + ra * 512 + ((mc * 128 + ks * 64 + l4 * 16) ^ ((ra & 7) << 4)));
        __builtin_amdgcn_s_setprio(1);
#pragma unroll
        for (int f = 0; f < 16; ++f) {
          int rb = f * 16 + l15;
          bf16x8_t bfr = *(const bf16x8_t*)(
              lb + rb * 128 + ((ks * 64 + l4 * 16) ^ ((rb & 7) << 4)));
          hacc[f] = __builtin_amdgcn_mfma_f32_16x16x32_bf16(af, bfr, hacc[f], 0, 0, 0);
        }
        __builtin_amdgcn_s_setprio(0);
      }
      __builtin_amdgcn_s_barrier();
      __builtin_amdgcn_sched_barrier(0);
    }
    sdn[t] = dnp;
    __syncthreads();
    if (t < 64)
      sdn[t] = 1.0f / (sdn[t] + sdn[t + 64] + sdn[t + 128] + sdn[t + 192] + 65536.0f);
    __syncthreads();
    float rdn[4];
#pragma unroll
    for (int j = 0; j < 4; ++j) rdn[j] = sdn[wid * 16 + l4 * 4 + j];
#pragma unroll
    for (int f = 0; f < 16; ++f) {
      float vs = vsum[h * HD + f * 16 + l15];
#pragma unroll
      for (int j = 0; j < 4; ++j) oacc[f][j] += (hacc[f][j] + vs) * rdn[j];
    }
    __syncthreads();
    __builtin_amdgcn_sched_barrier(0);
    if (h < 3) {  // next head's tiles; waited at (h+1, mc=0)
      stage_la(h + 1);
      stage_lb(h + 1, 0, 0);
    }
  }
#pragma unroll
  for (int f = 0; f < 16; ++f)
#pragma unroll
    for (int j = 0; j < 4; ++j)
      out[(size_t)(n0 + wid * 16 + l4 * 4 + j) * HD + f * 16 + l15] =
          oacc[f][j] * 0.25f;
}

extern "C" void kernel_launch(void* const* d_in, const int* in_sizes, int n_in,
                              void* d_out, int out_size, void* d_ws, size_t ws_size,
                              hipStream_t stream) {
  const float* x  = (const float*)d_in[0];
  const float* Wq = (const float*)d_in[1];
  const float* bq = (const float*)d_in[2];
  const float* Wk = (const float*)d_in[3];
  const float* bk = (const float*)d_in[4];
  const float* Wv = (const float*)d_in[5];
  const float* bv = (const float*)d_in[6];
  float* out = (float*)d_out;
  char* ws = (char*)d_ws;

  // workspace layout (total ~474 MB; kvP aliases xb — k2 runs after k1 consumed xb)
  bf16_t* qn   = (bf16_t*)(ws);                 // [N][1024]        134,217,728 B
  bf16_t* knT2 = (bf16_t*)(ws + 134217728L);    // [4][2][1024][128][64]  134 MB
  bf16_t* vT2  = (bf16_t*)(ws + 268435456L);    // same layout            134 MB
  bf16_t* Wt   = (bf16_t*)(ws + 402653184L);    // [3][1024][512]     3,145,728 B
  bf16_t* kvTb = (bf16_t*)(ws + 406847488L);    // [4][256][256]        524,288 B
  float*  ksum = (float*) (ws + 407371776L);    // [4][256]               4,096 B
  float*  vsum = (float*) (ws + 407375872L);    // [4][256]               4,096 B
  bf16_t* xb   = (bf16_t*)(ws + 407379968L);    // [N][512]          67,108,864 B
  float*  kvP  = (float*) (ws + 407379968L);    // [512][16384] f32  33,554,432 B (alias xb)

  hipMemsetAsync(ksum, 0, 8192, stream);  // ksum + vsum contiguous

  k0_wt  <<<dim3(32, 16, 3), 256, 0, stream>>>(Wq, Wk, Wv, Wt);
  k0b_xb <<<dim3(16384),     256, 0, stream>>>(x, xb);
  k1_qkv <<<dim3(6144),      512, 0, stream>>>(xb, Wt, bq, bk, bv, qn, knT2, vT2, ksum, vsum);
  k2_kv  <<<dim3(4, 4, 32),  256, 0, stream>>>(knT2, vT2, kvP);
  k3_red <<<dim3(256),       256, 0, stream>>>(kvP, kvTb);
  k4_out <<<dim3(1024),      256, 0, stream>>>(qn, kvTb, ksum, vsum, out);
}